// Round 1
// baseline (167.636 us; speedup 1.0000x reference)
//
#include <hip/hip_runtime.h>
#include <stdint.h>

// Problem constants (fixed by setup_inputs)
#define N_DE 12288
#define M_X  2048
#define D_K  128

typedef __attribute__((ext_vector_type(8))) short short8;
typedef __attribute__((ext_vector_type(4))) float f32x4;

// RBF constants: sum_b exp(-0.5/b * d2), b in {10, 512}
#define RBF_C1 (-0.05f)
#define RBF_C2 (-0.0009765625f)

// ---------------- prep: f32 -> bf16 (RNE) + row square-norms ----------------
__device__ inline ushort f32_to_bf16_rne(float f) {
    uint32_t x = __float_as_uint(f);
    uint32_t r = (x + 0x7fffu + ((x >> 16) & 1u)) >> 16;
    return (ushort)r;
}

__global__ __launch_bounds__(128) void prep_kernel(const float* __restrict__ src,
                                                   ushort* __restrict__ dst,
                                                   float* __restrict__ sq) {
    const int row = blockIdx.x;
    const int t = threadIdx.x;  // 128 threads = 2 waves
    float v = src[(size_t)row * D_K + t];
    ushort u = f32_to_bf16_rne(v);
    dst[(size_t)row * D_K + t] = u;
    float vb = __uint_as_float(((uint32_t)u) << 16);
    float s = vb * vb;
    #pragma unroll
    for (int off = 32; off; off >>= 1) s += __shfl_xor(s, off, 64);
    __shared__ float r2[2];
    if ((t & 63) == 0) r2[t >> 6] = s;
    __syncthreads();
    if (t == 0) sq[row] = r2[0] + r2[1];
}

// ---------------- fused GEMM + RBF + reduce ----------------
// A [MA x 128] bf16 row-major, B [NB x 128] bf16 row-major (both are "rows x K";
// C[i,j] = dot(A_i, B_j)).  MODE 0: total sum with triangular weighting -> atomicAdd
// scalar.  MODE 1: per-row (i) sums -> atomicAdd rowsum[i].
template <int MODE>
__global__ __launch_bounds__(256) void rbf_gemm(const ushort* __restrict__ A,
                                                const ushort* __restrict__ B,
                                                const float* __restrict__ sqA,
                                                const float* __restrict__ sqB,
                                                float* __restrict__ total_sum,
                                                float* __restrict__ row_sum) {
    const int bi = blockIdx.x;  // row tile
    const int bj = blockIdx.y;  // col tile
    if (MODE == 0 && bj < bi) return;  // triangular: only bj >= bi

    __shared__ short A_lds[128 * 128];  // 32 KB, swizzled chunks
    __shared__ short B_lds[128 * 128];  // 32 KB
    __shared__ float red[4];

    const int lane = threadIdx.x & 63;
    const int wave = threadIdx.x >> 6;  // 4 waves
    const int wr = wave >> 1;           // wave row 0..1 (64-row strip)
    const int wc = wave & 1;            // wave col 0..1
    const int cl = lane & 15;
    const int rh = lane >> 4;  // 0..3

    // ---- stage both tiles: LDS linear dest, pre-swizzled global source ----
    // LDS layout: byte p -> row = p>>8, chunk16 = (p>>4)&15 holds global
    // chunk (chunk16 ^ (row&7)) of that row.
    {
        const int row0a = bi * 128;
        const int row0b = bj * 128;
        #pragma unroll
        for (int it = 0; it < 8; ++it) {
            const int seg = wave * 8 + it;          // 0..31, 1 KB each
            const int row = seg * 4 + (lane >> 4);  // 4 rows per segment
            const int chunk = lane & 15;
            const int sc = chunk ^ (row & 7);
            const ushort* srcA = A + (size_t)(row0a + row) * D_K + sc * 8;
            const ushort* srcB = B + (size_t)(row0b + row) * D_K + sc * 8;
            __builtin_amdgcn_global_load_lds((const uint32_t*)srcA,
                                             (uint32_t*)(A_lds + seg * 512), 16, 0, 0);
            __builtin_amdgcn_global_load_lds((const uint32_t*)srcB,
                                             (uint32_t*)(B_lds + seg * 512), 16, 0, 0);
        }
    }
    __syncthreads();

    // ---- MFMA: 4 K-steps of 32, each wave 4x4 fragments of 16x16 ----
    f32x4 acc[4][4] = {};
    #pragma unroll
    for (int ks = 0; ks < 4; ++ks) {
        short8 a[4], b[4];
        #pragma unroll
        for (int m = 0; m < 4; ++m) {
            const int ar = wr * 64 + m * 16 + cl;
            const int ca = (ks * 4 + rh) ^ (ar & 7);
            a[m] = *(const short8*)&A_lds[ar * 128 + ca * 8];
            const int br = wc * 64 + m * 16 + cl;
            const int cb = (ks * 4 + rh) ^ (br & 7);
            b[m] = *(const short8*)&B_lds[br * 128 + cb * 8];
        }
        #pragma unroll
        for (int m = 0; m < 4; ++m)
            #pragma unroll
            for (int n = 0; n < 4; ++n)
                acc[m][n] = __builtin_amdgcn_mfma_f32_16x16x32_bf16(a[m], b[n], acc[m][n], 0, 0, 0);
    }

    // ---- epilogue: d2 = sqA[i] + sqB[j] - 2*dot; k = exp(C1 d2) + exp(C2 d2)
    // C/D layout (m89/m91): col = lane&15, row = (lane>>4)*4 + reg
    float sqa[4][4];
    float sqb[4];
    #pragma unroll
    for (int m = 0; m < 4; ++m)
        #pragma unroll
        for (int r = 0; r < 4; ++r)
            sqa[m][r] = sqA[bi * 128 + wr * 64 + m * 16 + rh * 4 + r];
    #pragma unroll
    for (int n = 0; n < 4; ++n)
        sqb[n] = sqB[bj * 128 + wc * 64 + n * 16 + cl];

    if (MODE == 0) {
        float s = 0.f;
        #pragma unroll
        for (int m = 0; m < 4; ++m)
            #pragma unroll
            for (int n = 0; n < 4; ++n)
                #pragma unroll
                for (int r = 0; r < 4; ++r) {
                    float d2 = fmaf(-2.f, acc[m][n][r], sqa[m][r] + sqb[n]);
                    s += __expf(RBF_C1 * d2) + __expf(RBF_C2 * d2);
                }
        #pragma unroll
        for (int off = 32; off; off >>= 1) s += __shfl_xor(s, off, 64);
        if (lane == 0) red[wave] = s;
        __syncthreads();
        if (threadIdx.x == 0) {
            float w = (bi == bj) ? 1.f : 2.f;
            atomicAdd(total_sum, w * (red[0] + red[1] + red[2] + red[3]));
        }
    } else {
        // per-row sums over this block's 128 columns
        #pragma unroll
        for (int m = 0; m < 4; ++m)
            #pragma unroll
            for (int r = 0; r < 4; ++r) {
                float rs = 0.f;
                #pragma unroll
                for (int n = 0; n < 4; ++n) {
                    float d2 = fmaf(-2.f, acc[m][n][r], sqa[m][r] + sqb[n]);
                    rs += __expf(RBF_C1 * d2) + __expf(RBF_C2 * d2);
                }
                rs += __shfl_xor(rs, 1, 64);
                rs += __shfl_xor(rs, 2, 64);
                rs += __shfl_xor(rs, 4, 64);
                rs += __shfl_xor(rs, 8, 64);
                if (cl == 0)
                    atomicAdd(&row_sum[bi * 128 + wr * 64 + m * 16 + rh * 4 + r], rs);
            }
    }
}

// ---------------- finalize ----------------
__global__ __launch_bounds__(256) void finalize_kernel(const float* __restrict__ kxx,
                                                       const float* __restrict__ kxy,
                                                       float* __restrict__ out) {
    const int i = blockIdx.x * 256 + threadIdx.x;
    if (i < M_X) {
        const float inv_nn = 1.f / ((float)N_DE * (float)N_DE);
        const float inv_n = 1.f / (float)N_DE;
        out[i] = kxx[0] * inv_nn + 2.f - 2.f * (kxy[i] * inv_n);
    }
}

extern "C" void kernel_launch(void* const* d_in, const int* in_sizes, int n_in,
                              void* d_out, int out_size, void* d_ws, size_t ws_size,
                              hipStream_t stream) {
    const float* De = (const float*)d_in[0];
    const float* X = (const float*)d_in[1];
    float* out = (float*)d_out;
    char* ws = (char*)d_ws;

    ushort* De_b = (ushort*)(ws);                 // 12288*128*2 = 3,145,728
    ushort* X_b  = (ushort*)(ws + 3145728);       // 2048*128*2  =   524,288
    float* sq_de = (float*)(ws + 3670016);        // 12288*4     =    49,152
    float* sq_x  = (float*)(ws + 3719168);        // 2048*4      =     8,192
    float* kxx_s = (float*)(ws + 3727360);        // 4 (padded to 256)
    float* kxy_s = (float*)(ws + 3727616);        // 2048*4      =     8,192

    // zero the atomic accumulators (ws is poisoned 0xAA before every launch)
    hipMemsetAsync(ws + 3727360, 0, 256 + 8192, stream);

    prep_kernel<<<N_DE, 128, 0, stream>>>(De, De_b, sq_de);
    prep_kernel<<<M_X, 128, 0, stream>>>(X, X_b, sq_x);

    // kxx: De x De, triangular tiles only (bj >= bi), weight 2 off-diagonal
    rbf_gemm<0><<<dim3(N_DE / 128, N_DE / 128), 256, 0, stream>>>(
        De_b, De_b, sq_de, sq_de, kxx_s, nullptr);
    // kxy: X x De, per-row sums
    rbf_gemm<1><<<dim3(M_X / 128, N_DE / 128), 256, 0, stream>>>(
        X_b, De_b, sq_x, sq_de, nullptr, kxy_s);

    finalize_kernel<<<M_X / 256, 256, 0, stream>>>(kxx_s, kxy_s, out);
}

// Round 2
// 120.479 us; speedup vs baseline: 1.3914x; 1.3914x over previous
//
#include <hip/hip_runtime.h>
#include <stdint.h>

// Problem constants (fixed by setup_inputs)
#define N_DE 12288
#define M_X  2048
#define D_K  128

typedef __attribute__((ext_vector_type(8))) short short8;
typedef __attribute__((ext_vector_type(4))) float f32x4;

// exp2-domain RBF constants: k = 2^(L1*d2) + 2^(L2*d2), L = -0.5/b * log2(e)
#define L1 (-0.07213475204444817f)
#define L2 (-0.0014088819735243783f)
#define M2L1 (0.14426950408889634f)   // -2*L1
#define M2L2 (0.0028177639470487566f) // -2*L2

__device__ inline float exp2_fast(float x) {
    float r;
    asm("v_exp_f32 %0, %1" : "=v"(r) : "v"(x));
    return r;
}

__device__ inline ushort f32_to_bf16_rne(float f) {
    uint32_t x = __float_as_uint(f);
    uint32_t r = (x + 0x7fffu + ((x >> 16) & 1u)) >> 16;
    return (ushort)r;
}

// ---------------- prep: f32 -> bf16 (RNE) + row square-norms + zero accums ----
// grid: (12288+2048)/4 blocks of 256; wave w handles row blockIdx*4+w.
__global__ __launch_bounds__(256) void prep_kernel(const float* __restrict__ De,
                                                   const float* __restrict__ X,
                                                   uint32_t* __restrict__ De_b,
                                                   uint32_t* __restrict__ X_b,
                                                   float* __restrict__ sq_de,
                                                   float* __restrict__ sq_x,
                                                   float* __restrict__ kxx_s,
                                                   float* __restrict__ kxy_s) {
    // fold accumulator zeroing into block 0 (runs before gemm via stream order)
    if (blockIdx.x == 0) {
        #pragma unroll
        for (int k = 0; k < 8; ++k) kxy_s[k * 256 + threadIdx.x] = 0.f;
        if (threadIdx.x == 0) kxx_s[0] = 0.f;
    }
    const int wave = threadIdx.x >> 6;
    const int lane = threadIdx.x & 63;
    const int g = blockIdx.x * 4 + wave;  // global row 0..14335
    const float* src;
    uint32_t* dst;
    float* sq;
    int row;
    if (g < N_DE) { src = De; dst = De_b; sq = sq_de; row = g; }
    else          { src = X;  dst = X_b;  sq = sq_x;  row = g - N_DE; }
    float2 v = *(const float2*)&src[(size_t)row * D_K + lane * 2];
    uint32_t u0 = f32_to_bf16_rne(v.x);
    uint32_t u1 = f32_to_bf16_rne(v.y);
    dst[(size_t)row * 64 + lane] = u0 | (u1 << 16);
    float b0 = __uint_as_float(u0 << 16);
    float b1 = __uint_as_float(u1 << 16);
    float s = b0 * b0 + b1 * b1;
    #pragma unroll
    for (int off = 32; off; off >>= 1) s += __shfl_xor(s, off, 64);
    if (lane == 0) sq[row] = s;
}

// ---------------- fused streaming GEMM + RBF + reduce ----------------
// Block: 128-row A strip x chunk of up to 8 B-subtiles (64 cols each), K=128.
// A staged to LDS once, A-fragments held in registers across the chunk.
// B double-buffered in LDS (16 KB each). 4 waves in 2x2 (64 rows x 32 cols each).
// blockIdx.x < 96: kxx strip (A=De, triangular, weight 2 off-diag);
// blockIdx.x >= 96: kxy strip (A=X, full, per-row sums).
__global__ __launch_bounds__(256, 2) void rbf_gemm(const ushort* __restrict__ De_b,
                                                   const ushort* __restrict__ X_b,
                                                   const float* __restrict__ sq_de,
                                                   const float* __restrict__ sq_x,
                                                   float* __restrict__ kxx_s,
                                                   float* __restrict__ kxy_s) {
    const int sx = blockIdx.x;
    const int chunk = blockIdx.y;
    const bool is_kxx = (sx < 96);
    const int strip = is_kxx ? sx : sx - 96;
    int j64s, nsub;
    if (is_kxx) {
        const int start = 2 * strip + chunk * 8;
        if (start >= 192) return;
        j64s = start;
        nsub = 192 - start; if (nsub > 8) nsub = 8;
    } else {
        j64s = chunk * 8;
        nsub = 8;
    }

    __shared__ short A_lds[128 * 128];     // 32 KB
    __shared__ short B_lds[2][64 * 128];   // 2 x 16 KB
    __shared__ float red[4];

    const int lane = threadIdx.x & 63;
    const int wave = threadIdx.x >> 6;
    const int wr = wave >> 1;  // 0..1: 64-row strip
    const int wc = wave & 1;   // 0..1: 32-col strip
    const int cl = lane & 15;
    const int rh = lane >> 4;  // 0..3

    const ushort* Ap = (is_kxx ? De_b : X_b) + (size_t)strip * 128 * D_K;
    const float* sqAp = (is_kxx ? sq_de : sq_x) + strip * 128;

    // ---- stage A (32 segs of 1 KB) + B[0] (16 segs), linear LDS dest,
    //      pre-swizzled global source: chunk16 c holds global chunk c^(row&7) ----
    {
        const int sl_chunk = lane & 15;
        const int sl_roff = lane >> 4;
        #pragma unroll
        for (int it = 0; it < 8; ++it) {
            const int seg = wave * 8 + it;
            const int row = seg * 4 + sl_roff;
            const int sc = sl_chunk ^ (row & 7);
            __builtin_amdgcn_global_load_lds((const uint32_t*)(Ap + (size_t)row * D_K + sc * 8),
                                             (uint32_t*)(A_lds + seg * 512), 16, 0, 0);
        }
        const size_t brow0 = (size_t)j64s * 64;
        #pragma unroll
        for (int it = 0; it < 4; ++it) {
            const int seg = wave * 4 + it;
            const int row = seg * 4 + sl_roff;
            const int sc = sl_chunk ^ (row & 7);
            __builtin_amdgcn_global_load_lds((const uint32_t*)(De_b + (brow0 + row) * D_K + sc * 8),
                                             (uint32_t*)(B_lds[0] + seg * 512), 16, 0, 0);
        }
    }
    __syncthreads();  // drains vmcnt -> A and B0 resident

    // ---- A fragments to registers (held across all subtiles) ----
    short8 afr[4][4];  // [m][ks], 64 VGPRs
    #pragma unroll
    for (int m = 0; m < 4; ++m) {
        const int ar = wr * 64 + m * 16 + cl;
        #pragma unroll
        for (int ks = 0; ks < 4; ++ks) {
            const int ca = (ks * 4 + rh) ^ (ar & 7);
            afr[m][ks] = *(const short8*)&A_lds[ar * 128 + ca * 8];
        }
    }
    // per-lane row constants: pa_b[m][r] = L_b * sqA[row(m,r)]
    float pa1[4][4], pa2[4][4];
    #pragma unroll
    for (int m = 0; m < 4; ++m)
        #pragma unroll
        for (int r = 0; r < 4; ++r) {
            const float sa = sqAp[wr * 64 + m * 16 + rh * 4 + r];
            pa1[m][r] = L1 * sa;
            pa2[m][r] = L2 * sa;
        }

    float rowacc[4][4] = {};  // per-lane row partial sums (unweighted)
    float smix = 0.f;         // diagonal-tile weighted partials (kxx only)
    const int gi_base = strip * 128 + wr * 64;  // global row for weights

    int cur = 0;
    for (int t = 0; t < nsub; ++t) {
        const int j64 = j64s + t;
        // prefetch column square-norms for this subtile
        const float sqb0 = sq_de[j64 * 64 + wc * 32 + cl];
        const float sqb1 = sq_de[j64 * 64 + wc * 32 + 16 + cl];
        // issue next B staging (hidden under this subtile's compute)
        if (t + 1 < nsub) {
            const size_t brow0 = (size_t)(j64 + 1) * 64;
            const int sl_chunk = lane & 15;
            const int sl_roff = lane >> 4;
            #pragma unroll
            for (int it = 0; it < 4; ++it) {
                const int seg = wave * 4 + it;
                const int row = seg * 4 + sl_roff;
                const int sc = sl_chunk ^ (row & 7);
                __builtin_amdgcn_global_load_lds((const uint32_t*)(De_b + (brow0 + row) * D_K + sc * 8),
                                                 (uint32_t*)(B_lds[cur ^ 1] + seg * 512), 16, 0, 0);
            }
        }
        // B fragments for this subtile
        short8 bfr[2][4];
        #pragma unroll
        for (int n = 0; n < 2; ++n) {
            const int br = wc * 32 + n * 16 + cl;
            #pragma unroll
            for (int ks = 0; ks < 4; ++ks) {
                const int cb = (ks * 4 + rh) ^ (br & 7);
                bfr[n][ks] = *(const short8*)&B_lds[cur][br * 128 + cb * 8];
            }
        }
        // MFMA: 4 m x 2 n x 4 ks
        f32x4 acc[4][2] = {};
        #pragma unroll
        for (int ks = 0; ks < 4; ++ks)
            #pragma unroll
            for (int m = 0; m < 4; ++m)
                #pragma unroll
                for (int n = 0; n < 2; ++n)
                    acc[m][n] = __builtin_amdgcn_mfma_f32_16x16x32_bf16(afr[m][ks], bfr[n][ks], acc[m][n], 0, 0, 0);

        // epilogue: k = 2^(L1*d2) + 2^(L2*d2), d2 = sqa+sqb-2*dot
        const float pb1[2] = {L1 * sqb0, L1 * sqb1};
        const float pb2[2] = {L2 * sqb0, L2 * sqb1};
        const bool mixed = is_kxx && (j64 < 2 * strip + 2);
        if (!mixed) {
            #pragma unroll
            for (int m = 0; m < 4; ++m)
                #pragma unroll
                for (int n = 0; n < 2; ++n) {
                    const float c1 = pa1[m][0], c2 = pa2[m][0];  // placeholder; real per-r below
                    (void)c1; (void)c2;
                    #pragma unroll
                    for (int r = 0; r < 4; ++r) {
                        const float v = acc[m][n][r];
                        const float k1 = exp2_fast(fmaf(M2L1, v, pa1[m][r] + pb1[n]));
                        const float k2 = exp2_fast(fmaf(M2L2, v, pa2[m][r] + pb2[n]));
                        rowacc[m][r] += k1 + k2;
                    }
                }
        } else {
            const int gj_base = j64 * 64 + wc * 32;
            #pragma unroll
            for (int m = 0; m < 4; ++m)
                #pragma unroll
                for (int n = 0; n < 2; ++n)
                    #pragma unroll
                    for (int r = 0; r < 4; ++r) {
                        const float v = acc[m][n][r];
                        const float k1 = exp2_fast(fmaf(M2L1, v, pa1[m][r] + pb1[n]));
                        const float k2 = exp2_fast(fmaf(M2L2, v, pa2[m][r] + pb2[n]));
                        const int gi = gi_base + m * 16 + rh * 4 + r;
                        const int gj = gj_base + n * 16 + cl;
                        const float w = (gj > gi) ? 2.f : ((gj == gi) ? 1.f : 0.f);
                        smix = fmaf(w, k1 + k2, smix);
                    }
        }
        __syncthreads();  // drains staged B[cur^1]; all waves done reading B[cur]
        cur ^= 1;
    }

    // ---- block reduction / output ----
    if (is_kxx) {
        float tot = smix;
        #pragma unroll
        for (int m = 0; m < 4; ++m)
            #pragma unroll
            for (int r = 0; r < 4; ++r) tot += 2.f * rowacc[m][r];
        #pragma unroll
        for (int off = 32; off; off >>= 1) tot += __shfl_xor(tot, off, 64);
        if (lane == 0) red[wave] = tot;
        __syncthreads();
        if (threadIdx.x == 0) atomicAdd(kxx_s, red[0] + red[1] + red[2] + red[3]);
    } else {
        #pragma unroll
        for (int m = 0; m < 4; ++m)
            #pragma unroll
            for (int r = 0; r < 4; ++r) {
                float rs = rowacc[m][r];
                rs += __shfl_xor(rs, 1, 64);
                rs += __shfl_xor(rs, 2, 64);
                rs += __shfl_xor(rs, 4, 64);
                rs += __shfl_xor(rs, 8, 64);
                if (cl == 0)
                    atomicAdd(&kxy_s[strip * 128 + wr * 64 + m * 16 + rh * 4 + r], rs);
            }
    }
}

// ---------------- finalize ----------------
__global__ __launch_bounds__(256) void finalize_kernel(const float* __restrict__ kxx,
                                                       const float* __restrict__ kxy,
                                                       float* __restrict__ out) {
    const int i = blockIdx.x * 256 + threadIdx.x;
    if (i < M_X) {
        const float inv_nn = 1.f / ((float)N_DE * (float)N_DE);
        const float inv_n = 1.f / (float)N_DE;
        out[i] = kxx[0] * inv_nn + 2.f - 2.f * (kxy[i] * inv_n);
    }
}

extern "C" void kernel_launch(void* const* d_in, const int* in_sizes, int n_in,
                              void* d_out, int out_size, void* d_ws, size_t ws_size,
                              hipStream_t stream) {
    const float* De = (const float*)d_in[0];
    const float* X = (const float*)d_in[1];
    float* out = (float*)d_out;
    char* ws = (char*)d_ws;

    ushort* De_b = (ushort*)(ws);                 // 3,145,728 B
    ushort* X_b  = (ushort*)(ws + 3145728);       //   524,288 B
    float* sq_de = (float*)(ws + 3670016);        //    49,152 B
    float* sq_x  = (float*)(ws + 3719168);        //     8,192 B
    float* kxx_s = (float*)(ws + 3727360);        //       256 B
    float* kxy_s = (float*)(ws + 3727616);        //     8,192 B

    prep_kernel<<<(N_DE + M_X) / 4, 256, 0, stream>>>(De, X, (uint32_t*)De_b, (uint32_t*)X_b,
                                                      sq_de, sq_x, kxx_s, kxy_s);
    rbf_gemm<<<dim3(96 + M_X / 128, 24), 256, 0, stream>>>(De_b, X_b, sq_de, sq_x, kxx_s, kxy_s);
    finalize_kernel<<<M_X / 256, 256, 0, stream>>>(kxx_s, kxy_s, out);
}